// Round 12
// baseline (211.643 us; speedup 1.0000x reference)
//
#include <hip/hip_runtime.h>
#include <math.h>

// Problem constants (fixed by the reference file)
#define NN 100000
#define EE 1600000
#define DIM 128

// Partition parameters
#define BK 256                 // nodes per coarse bucket (dst >> 8)
#define NBK2 392               // ceil(NN / 256)
#define NCH 256                // gHist columns
#define SCN (NBK2 * NCH)       // 100352 = 98 * 1024 exactly
#define NSB 98                 // scan blocks

#define N_TILES 782            // ceil(NN / 128)
#define FT_BLOCKS 512          // k_front grid (2 blocks/CU, all resident)
#define HEPB 3125              // EE / FT_BLOCKS (exact)

// LDS geometry for k_front: A tile [128 rows][272 B] + B tile [128][272 B]
#define LDS_ROW 272            // 256 B of fp16 + 16 B pad (bank stagger)
#define LDS_B_OFF 34816        // 128 * 272
#define LDS_TOT 69632          // 2 * 34816

// Edge payload encoding (32-bit):
//   binned: src(17 bits) | dloc(8 bits) << 17
//   pack:   src(17 bits) | fp16(w * rowscale[src]) << 17   (>0 -> sign bit 0)
#define SRC_MASK 0x1FFFFu

typedef _Float16 half8 __attribute__((ext_vector_type(8)));
typedef _Float16 half4v __attribute__((ext_vector_type(4)));
typedef signed char char8 __attribute__((ext_vector_type(8)));
typedef float f32x4 __attribute__((ext_vector_type(4)));

// ---------------------------------------------------------------------------
// Kernel 0: Bt[n*128+k] = W[n*128+k] * mask[k], cast fp16.
// ---------------------------------------------------------------------------
__global__ __launch_bounds__(256) void k_wt(const float* __restrict__ W,
                                            const float* __restrict__ mask,
                                            _Float16* __restrict__ Bt) {
    int o = blockIdx.x * 256 + threadIdx.x;
    if (o < DIM * DIM) Bt[o] = (_Float16)(W[o] * mask[o & 127]);
}

// ---------------------------------------------------------------------------
// Kernel 1 (v3): 512 blocks x 512 threads, ALL resident (2 blocks/CU).
// Per block: stage B (Bt) into LDS ONCE; process tiles {bx, bx+512}
// (128 rows each: stage A coalesced->fp16 LDS, MFMA, int8-quant epilogue,
// coalesced writeback); then histogram 3125 edges into LDS and atomically
// merge into gHist column bx>>1 (gHist pre-zeroed by memset).
// ---------------------------------------------------------------------------
__global__ __launch_bounds__(512, 4) void k_front(const float* __restrict__ feat,
                                                  const _Float16* __restrict__ Bt,
                                                  const float* __restrict__ attn,
                                                  signed char* __restrict__ hq,
                                                  float* __restrict__ scf,
                                                  _Float16* __restrict__ sv16,
                                                  const int* __restrict__ dst,
                                                  int* __restrict__ gHist) {
    __shared__ char smem[LDS_TOT];
    const int bx = blockIdx.x;
    const int t  = threadIdx.x;
    const int lane = t & 63;
    const int wv   = t >> 6;              // 0..7
    const int l15  = lane & 15;
    const int quad = lane >> 4;

    // ---- stage B once: Bt (fp16) -> LDS tile, coalesced int4 loads ----
#pragma unroll
    for (int i = 0; i < 4; ++i) {
        int idx = i * FT_BLOCKS + t;      // 0..2047
        int r   = idx >> 4;               // 0..127
        int c8  = idx & 15;               // 16-B chunk
        int4 v = ((const int4*)(Bt + (size_t)r * DIM))[c8];
        *(int4*)(smem + LDS_B_OFF + r * LDS_ROW + c8 * 16) = v;
    }

    float avv[8];
#pragma unroll
    for (int nt = 0; nt < 8; ++nt) avv[nt] = attn[nt * 16 + l15];

    for (int tile = bx; tile < N_TILES; tile += FT_BLOCKS) {
        const int rowBase = tile * 128;

        // ---- stage A: feat rows -> fp16 LDS tile, coalesced float4 ----
#pragma unroll
        for (int i = 0; i < 8; ++i) {
            int idx  = i * FT_BLOCKS + t; // 0..4095
            int r    = idx >> 5;          // 0..127
            int c4   = idx & 31;          // float4 column
            int rowg = rowBase + r;
            float4 f = (rowg < NN)
                           ? ((const float4*)(feat + (size_t)rowg * DIM))[c4]
                           : make_float4(0.f, 0.f, 0.f, 0.f);
            half4v h;
            h[0] = (_Float16)f.x; h[1] = (_Float16)f.y;
            h[2] = (_Float16)f.z; h[3] = (_Float16)f.w;
            *(half4v*)(smem + r * LDS_ROW + c4 * 8) = h;
        }
        __syncthreads();

        const int row0 = rowBase + wv * 16;
        f32x4 acc[8];
#pragma unroll
        for (int nt = 0; nt < 8; ++nt) acc[nt] = (f32x4){0.f, 0.f, 0.f, 0.f};

        const char* Abase = smem + (wv * 16 + l15) * LDS_ROW + quad * 16;
        const char* Bbase = smem + LDS_B_OFF + l15 * LDS_ROW + quad * 16;

#pragma unroll
        for (int kc = 0; kc < 4; ++kc) {
            half8 a = *(const half8*)(Abase + kc * 64);
#pragma unroll
            for (int nt = 0; nt < 8; ++nt) {
                half8 b = *(const half8*)(Bbase + nt * 16 * LDS_ROW + kc * 64);
                acc[nt] = __builtin_amdgcn_mfma_f32_16x16x32_f16(a, b, acc[nt], 0, 0, 0);
            }
        }

        // epilogue: attention score + int8 quantization, staged via LDS
        char* qslice = smem + wv * (16 * LDS_ROW);   // wave's dead A-slice
#pragma unroll
        for (int r = 0; r < 4; ++r) {
            int row = row0 + quad * 4 + r;
            float p = 0.f, m = 0.f;
#pragma unroll
            for (int nt = 0; nt < 8; ++nt) {
                p += acc[nt][r] * avv[nt];
                m = fmaxf(m, fabsf(acc[nt][r]));
            }
            p += __shfl_xor(p, 1, 64);
            p += __shfl_xor(p, 2, 64);
            p += __shfl_xor(p, 4, 64);
            p += __shfl_xor(p, 8, 64);
            m = fmaxf(m, __shfl_xor(m, 1, 64));
            m = fmaxf(m, __shfl_xor(m, 2, 64));
            m = fmaxf(m, __shfl_xor(m, 4, 64));
            m = fmaxf(m, __shfl_xor(m, 8, 64));
            if (l15 == 0 && row < NN) {
                float lr = (p > 0.f) ? p : 0.01f * p;
                sv16[row] = (_Float16)__expf(lr);   // softmax numerator
                scf[row]  = m * (1.f / 127.f);      // per-row dequant scale
            }
            const float inv_s = (m > 0.f) ? (127.f / m) : 0.f;
#pragma unroll
            for (int nt = 0; nt < 8; ++nt) {
                float qv = rintf(acc[nt][r] * inv_s);
                qv = fminf(fmaxf(qv, -127.f), 127.f);
                qslice[(quad * 4 + r) * 128 + nt * 16 + l15] = (signed char)(int)qv;
            }
        }
        // coalesced writeback: lane covers 32 contiguous bytes of one row
        {
            const int rowg = row0 + (lane >> 2);
            if (rowg < NN) {
                int4 v0 = *(const int4*)(qslice + lane * 32);
                int4 v1 = *(const int4*)(qslice + lane * 32 + 16);
                int4* dp = (int4*)(hq + (size_t)rowg * DIM + (lane & 3) * 32);
                dp[0] = v0;
                dp[1] = v1;
            }
        }
        __syncthreads();   // A region consumed before next tile / hist reuse
    }

    // ---- fused coarse-bucket histogram over this block's edge span ----
    int* hist = (int*)smem;
    for (int i = t; i < NBK2; i += FT_BLOCKS) hist[i] = 0;
    __syncthreads();
    const int e0 = bx * HEPB;
    for (int e = e0 + t; e < e0 + HEPB; e += FT_BLOCKS)
        atomicAdd(&hist[dst[e] >> 8], 1);
    __syncthreads();
    const int col = bx >> 1;              // two blocks merge per column
    for (int i = t; i < NBK2; i += FT_BLOCKS)
        atomicAdd(&gHist[i * NCH + col], hist[i]);
}

// ---------------------------------------------------------------------------
// Kernel 2: exclusive scan of gHist (SCN = 98*1024 elements). Per-block sums
// land in bsum; consumers inline the 98-element bsum scan themselves.
// ---------------------------------------------------------------------------
__global__ __launch_bounds__(256) void k_scan_a(const int* __restrict__ deg,
                                                int* __restrict__ excl,
                                                int* __restrict__ bsum) {
    __shared__ int wsum[4];
    __shared__ int woff[4];
    const int t = threadIdx.x, b = blockIdx.x;
    const int base = b * 1024 + t * 4;
    int v0 = deg[base + 0];
    int v1 = deg[base + 1];
    int v2 = deg[base + 2];
    int v3 = deg[base + 3];
    int tsum = v0 + v1 + v2 + v3;

    const int lane = t & 63, w = t >> 6;
    int incl = tsum;
#pragma unroll
    for (int d = 1; d < 64; d <<= 1) {
        int n = __shfl_up(incl, d, 64);
        if (lane >= d) incl += n;
    }
    if (lane == 63) wsum[w] = incl;
    __syncthreads();
    if (t == 0) {
        int run = 0;
#pragma unroll
        for (int i = 0; i < 4; ++i) { woff[i] = run; run += wsum[i]; }
        bsum[b] = run;
    }
    __syncthreads();
    int texcl = incl - tsum + woff[w];
    excl[base + 0] = texcl;
    excl[base + 1] = texcl + v0;
    excl[base + 2] = texcl + v0 + v1;
    excl[base + 3] = texcl + v0 + v1 + v2;
}

// ---------------------------------------------------------------------------
// Inline 98-element exclusive scan of bsum into sboff (needs >=128 threads,
// two __syncthreads). Replaces a separate launch.
// ---------------------------------------------------------------------------
#define INLINE_BOFF_SCAN(bsum, sboff, swtop, t)                          \
    {                                                                    \
        const int lane_ = (t) & 63;                                      \
        int v_ = 0, incl_ = 0;                                           \
        if ((t) < 128) {                                                 \
            v_ = ((t) < NSB) ? (bsum)[(t)] : 0;                          \
            incl_ = v_;                                                  \
            _Pragma("unroll")                                            \
            for (int d_ = 1; d_ < 64; d_ <<= 1) {                        \
                int n_ = __shfl_up(incl_, d_, 64);                       \
                if (lane_ >= d_) incl_ += n_;                            \
            }                                                            \
            if ((t) == 63) (swtop) = incl_;                              \
        }                                                                \
        __syncthreads();                                                 \
        if ((t) < NSB) {                                                 \
            int add_ = ((t) >= 64) ? (swtop) : 0;                        \
            (sboff)[(t)] = incl_ - v_ + add_;                            \
        }                                                                \
        __syncthreads();                                                 \
    }

// ---------------------------------------------------------------------------
// Kernel 3: partition scatter. Private contiguous region per (bucket,block)
// -> full-line writebacks, LDS-only atomics. boff scan inlined.
// Payload: u32 = src | dloc<<17 (weight NOT carried — k_group reads sv16).
// NOTE: edge chunks here are NCH=256 columns; block b owns column b, edges
// [b*6250, (b+1)*6250) — matches gHist columns (each merged from 2 k_front
// half-chunks covering the same 6250-edge span).
// ---------------------------------------------------------------------------
#define EPB 6250               // EE / NCH
__global__ __launch_bounds__(1024) void k_bscatter(const int* __restrict__ src,
                                                   const int* __restrict__ dst,
                                                   const int* __restrict__ gOff,
                                                   const int* __restrict__ bsum,
                                                   unsigned* __restrict__ binned) {
    __shared__ int cur[NBK2];
    __shared__ int sboff[NSB];
    __shared__ int swtop;
    const int t = threadIdx.x, b = blockIdx.x;

    INLINE_BOFF_SCAN(bsum, sboff, swtop, t)

    for (int i = t; i < NBK2; i += 1024) {
        int idx = i * NCH + b;
        cur[i] = gOff[idx] + sboff[idx >> 10];
    }
    __syncthreads();
    const int e0 = b * EPB;
    int e1 = e0 + EPB; if (e1 > EE) e1 = EE;
    for (int e = e0 + t; e < e1; e += 1024) {
        int d  = dst[e];
        int si = src[e];
        int bk   = d >> 8;
        int dloc = d & (BK - 1);
        int pos = atomicAdd(&cur[bk], 1);
        binned[pos] = (unsigned)si | ((unsigned)dloc << 17);
    }
}

// ---------------------------------------------------------------------------
// Kernel 4: per-bucket exact CSR placement + node CSR pointers + per-node
// weight-sum (softmax denominator) via LDS f32 atomics. The pack weight is
// PRE-SCALED: w' = fp16(w * scf[src]) — int8 dequant folded into the edge
// weight, so k_agg's inner loop needs no scale lookups.
// ---------------------------------------------------------------------------
__global__ __launch_bounds__(1024) void k_group(const int* __restrict__ gOff,
                                                const int* __restrict__ bsum,
                                                const unsigned* __restrict__ binned,
                                                const _Float16* __restrict__ sv16,
                                                const float* __restrict__ scf,
                                                unsigned* __restrict__ pack,
                                                int* __restrict__ offs,
                                                float* __restrict__ lsum) {
    __shared__ int ldeg[BK];
    __shared__ float lsumSh[BK];
    __shared__ int wpart[4];
    __shared__ int sboff[NSB];
    __shared__ int swtop;
    const int bk = blockIdx.x;
    const int t  = threadIdx.x;

    INLINE_BOFF_SCAN(bsum, sboff, swtop, t)

    const int i0 = bk * NCH;
    const int base = gOff[i0] + sboff[i0 >> 10];
    int endp;
    if (bk == NBK2 - 1) endp = EE;
    else {
        int i1 = (bk + 1) * NCH;
        endp = gOff[i1] + sboff[i1 >> 10];
    }

    if (t < BK) { ldeg[t] = 0; lsumSh[t] = 0.f; }
    __syncthreads();
    for (int j = base + t; j < endp; j += 1024)
        atomicAdd(&ldeg[(binned[j] >> 17) & (BK - 1)], 1);
    __syncthreads();

    // scan of 256 bins: first 256 threads (4 waves) + cross-wave combine
    int v = 0, incl = 0;
    const int lane = t & 63;
    if (t < BK) {
        v = ldeg[t];
        incl = v;
#pragma unroll
        for (int d = 1; d < 64; d <<= 1) {
            int n = __shfl_up(incl, d, 64);
            if (lane >= d) incl += n;
        }
        if (lane == 63) wpart[t >> 6] = incl;
    }
    __syncthreads();
    if (t == 0) {
        int run = 0;
#pragma unroll
        for (int i = 0; i < 4; ++i) { int tmp = wpart[i]; wpart[i] = run; run += tmp; }
    }
    __syncthreads();
    if (t < BK) {
        int excl = incl - v + wpart[t >> 6];
        int c = base + excl;
        int n = bk * BK + t;
        if (n < NN) offs[n] = c;
        ldeg[t] = c;                       // becomes the placement cursor
    }
    if (bk == NBK2 - 1 && t == 0) offs[NN] = EE;
    __syncthreads();

    for (int j = base + t; j < endp; j += 1024) {
        unsigned e = binned[j];
        int dloc = (e >> 17) & (BK - 1);
        int si   = e & SRC_MASK;
        float w  = (float)sv16[si];
        float sc = scf[si];
        unsigned short wb =
            __builtin_bit_cast(unsigned short, (_Float16)(w * sc));
        atomicAdd(&lsumSh[dloc], w);
        int pos = atomicAdd(&ldeg[dloc], 1);
        pack[pos] = (unsigned)si | ((unsigned)wb << 17);
    }
    __syncthreads();
    if (t < BK) {
        int n = bk * BK + t;
        if (n < NN) lsum[n] = lsumSh[t];
    }
}

// ---------------------------------------------------------------------------
// Kernel 5 (v7): one wave per dst node, int8 rows, shfl-free inner loop,
// GRADUATED TAIL: exactly ceil(rem/4) independent predicated steps (was a
// fixed 16-slot pass — Poisson-16 degrees wasted ~6 fake slots/node of VALU).
// ---------------------------------------------------------------------------
#define TAIL_STEP(S)                                                        \
    {                                                                       \
        int idx_ = p + (S) * 4 + g;                                         \
        bool ok_ = idx_ < end;                                              \
        unsigned eb_ = pack[ok_ ? idx_ : last];                             \
        char8 q_ = *(const char8*)(hb + ((size_t)(eb_ & SRC_MASK) << 7));   \
        float wg_ = ok_ ? (float)__builtin_bit_cast(                        \
                              _Float16, (unsigned short)(eb_ >> 17))        \
                        : 0.f;                                              \
        _Pragma("unroll")                                                   \
        for (int k_ = 0; k_ < 8; ++k_)                                      \
            acc[k_] = fmaf((float)q_[k_], wg_, acc[k_]);                    \
    }

__global__ __launch_bounds__(256) void k_agg(const signed char* __restrict__ hq,
                                             const int* __restrict__ offs,
                                             const unsigned* __restrict__ pack,
                                             const float* __restrict__ lsum,
                                             float* __restrict__ out) {
    const int lane = threadIdx.x & 63;
    const int g    = lane >> 4;        // quarter-wave group 0..3
    const int li   = lane & 15;        // lane within group
    const int wid  = __builtin_amdgcn_readfirstlane(blockIdx.x * 4 + (threadIdx.x >> 6));
    if (wid >= NN) return;
    const int beg = __builtin_amdgcn_readfirstlane(offs[wid]);
    const int end = __builtin_amdgcn_readfirstlane(offs[wid + 1]);

    const signed char* hb = hq + li * 8;   // per-lane base (hoisted)
    float acc[8];
#pragma unroll
    for (int k = 0; k < 8; ++k) acc[k] = 0.f;

    int p = beg;
    // main: 16 edges per iteration, 4 gathers in flight, no predication
    for (; p + 16 <= end; p += 16) {
        unsigned eb[4];
#pragma unroll
        for (int s = 0; s < 4; ++s) eb[s] = pack[p + s * 4 + g];
        char8 q[4];
#pragma unroll
        for (int s = 0; s < 4; ++s)
            q[s] = *(const char8*)(hb + ((size_t)(eb[s] & SRC_MASK) << 7));
        float wg[4];
#pragma unroll
        for (int s = 0; s < 4; ++s)
            wg[s] = (float)__builtin_bit_cast(_Float16,
                                              (unsigned short)(eb[s] >> 17));
#pragma unroll
        for (int s = 0; s < 4; ++s)
#pragma unroll
            for (int k = 0; k < 8; ++k)
                acc[k] = fmaf((float)q[s][k], wg[s], acc[k]);
    }
    // graduated tail: ceil(rem/4) independent steps, wave-uniform branches
    const int rem = end - p;            // 0..15
    if (rem > 0) {
        const int last = end - 1;
        if (rem > 12)      { TAIL_STEP(0) TAIL_STEP(1) TAIL_STEP(2) TAIL_STEP(3) }
        else if (rem > 8)  { TAIL_STEP(0) TAIL_STEP(1) TAIL_STEP(2) }
        else if (rem > 4)  { TAIL_STEP(0) TAIL_STEP(1) }
        else               { TAIL_STEP(0) }
    }

    // cross-group combine: 4 groups hold partials for the same channels
#pragma unroll
    for (int k = 0; k < 8; ++k) {
        acc[k] += __shfl_xor(acc[k], 16, 64);
        acc[k] += __shfl_xor(acc[k], 32, 64);
    }

    const float l   = lsum[wid];
    const float inv = (l > 0.f) ? (1.0f / l) : 0.f;

    // store: group 0's 16 lanes write 32 B each -> contiguous 512 B per node
    if (g == 0) {
        float4 o0, o1;
        o0.x = fmaxf(acc[0] * inv, 0.f);
        o0.y = fmaxf(acc[1] * inv, 0.f);
        o0.z = fmaxf(acc[2] * inv, 0.f);
        o0.w = fmaxf(acc[3] * inv, 0.f);
        o1.x = fmaxf(acc[4] * inv, 0.f);
        o1.y = fmaxf(acc[5] * inv, 0.f);
        o1.z = fmaxf(acc[6] * inv, 0.f);
        o1.w = fmaxf(acc[7] * inv, 0.f);
        float4* op = (float4*)(out + (size_t)wid * DIM + li * 8);
        op[0] = o0;
        op[1] = o1;
    }
}

// ---------------------------------------------------------------------------
extern "C" void kernel_launch(void* const* d_in, const int* in_sizes, int n_in,
                              void* d_out, int out_size, void* d_ws, size_t ws_size,
                              hipStream_t stream) {
    const float* feat = (const float*)d_in[0];
    const float* mask = (const float*)d_in[1];
    const float* W    = (const float*)d_in[2];
    const float* attn = (const float*)d_in[3];
    const int*   src  = (const int*)d_in[4];
    const int*   dst  = (const int*)d_in[5];
    float* out = (float*)d_out;

    // Workspace carve-up (~28 MB total)
    char* ws = (char*)d_ws;
    size_t off = 0;
    auto alloc = [&](size_t bytes) -> void* {
        void* p = ws + off;
        off = (off + bytes + 511) & ~(size_t)511;
        return p;
    };
    signed char* hq  = (signed char*)alloc((size_t)NN * DIM);   // 12.8 MB
    float*   scf  = (float*)alloc((size_t)NN * 4);              // 0.4 MB
    float*   lsum = (float*)alloc((size_t)NN * 4);              // 0.4 MB
    _Float16* sv16 = (_Float16*)alloc((size_t)NN * 2);          // 0.2 MB
    _Float16* Bt   = (_Float16*)alloc((size_t)DIM * DIM * 2);
    int*     gOff  = (int*)alloc((size_t)SCN * 4);              // 401 KB
    int*     offs  = (int*)alloc((size_t)(NN + 1) * 4);
    int*     bsum  = (int*)alloc((size_t)NSB * 4);
    unsigned* binned = (unsigned*)alloc((size_t)EE * 4);        // 6.4 MB
    unsigned* pack   = (unsigned*)alloc((size_t)EE * 4);        // 6.4 MB

    hipMemsetAsync(gOff, 0, (size_t)SCN * 4, stream);           // hist zero
    k_wt<<<(DIM * DIM + 255) / 256, 256, 0, stream>>>(W, mask, Bt);
    k_front<<<FT_BLOCKS, 512, 0, stream>>>(feat, Bt, attn, hq, scf,
                                           sv16, dst, gOff);
    k_scan_a<<<NSB, 256, 0, stream>>>(gOff, gOff, bsum);
    k_bscatter<<<NCH, 1024, 0, stream>>>(src, dst, gOff, bsum, binned);
    k_group<<<NBK2, 1024, 0, stream>>>(gOff, bsum, binned, sv16, scf,
                                       pack, offs, lsum);
    k_agg<<<(NN + 3) / 4, 256, 0, stream>>>(hq, offs, pack, lsum, out);
}

// Round 13
// 203.921 us; speedup vs baseline: 1.0379x; 1.0379x over previous
//
#include <hip/hip_runtime.h>
#include <math.h>

// Problem constants (fixed by the reference file)
#define NN 100000
#define EE 1600000
#define DIM 128

// Partition parameters
#define BK 256                 // nodes per coarse bucket (dst >> 8)
#define NBK2 392               // ceil(NN / 256)
#define NCH 256                // edge-chunk blocks
#define EPB 6250               // EE / NCH
#define SCN (NBK2 * NCH)       // 100352 = 98 * 1024 exactly
#define NSB 98                 // scan blocks

#define GEMM_BLKS 782          // ceil(NN / 128)
#define FBLK 512               // k_front block size (8 waves)

// LDS geometry for k_front: A tile [128 rows][272 B] + B tile [128][272 B]
#define LDS_ROW 272            // 256 B of fp16 + 16 B pad (bank stagger)
#define LDS_B_OFF 34816        // 128 * 272
#define LDS_TOT 69632          // 2 * 34816

// Edge payload encoding (32-bit):
//   binned: src(17 bits) | dloc(8 bits) << 17
//   pack:   src(17 bits) | fp16(w * rowscale[src]) << 17   (>0 -> sign bit 0)
#define SRC_MASK 0x1FFFFu

typedef _Float16 half8 __attribute__((ext_vector_type(8)));
typedef _Float16 half4v __attribute__((ext_vector_type(4)));
typedef signed char char8 __attribute__((ext_vector_type(8)));
typedef float f32x4 __attribute__((ext_vector_type(4)));

// ---------------------------------------------------------------------------
// Kernel 0: Bt[n*128+k] = W[n*128+k] * mask[k], cast fp16.
// ---------------------------------------------------------------------------
__global__ __launch_bounds__(256) void k_wt(const float* __restrict__ W,
                                            const float* __restrict__ mask,
                                            _Float16* __restrict__ Bt) {
    int o = blockIdx.x * 256 + threadIdx.x;
    if (o < DIM * DIM) Bt[o] = (_Float16)(W[o] * mask[o & 127]);
}

// ---------------------------------------------------------------------------
// Kernel 1 (round-11 form — best measured): blocks [0, GEMM_BLKS) = MFMA
// GEMM over 128 rows each, LDS-staged A and B with coalesced loads; int8
// per-row quant epilogue staged through LDS, coalesced 32-B writeback.
// Blocks [GEMM_BLKS, +NCH) = coarse dst histogram. (Persistent-block variant
// regressed in round 12 — 782/512 tile imbalance; do not reintroduce.)
// ---------------------------------------------------------------------------
__global__ __launch_bounds__(512, 4) void k_front(const float* __restrict__ feat,
                                                  const _Float16* __restrict__ Bt,
                                                  const float* __restrict__ attn,
                                                  signed char* __restrict__ hq,
                                                  float* __restrict__ scf,
                                                  _Float16* __restrict__ sv16,
                                                  const int* __restrict__ dst,
                                                  int* __restrict__ gHist) {
    __shared__ char smem[LDS_TOT];
    const int bx = blockIdx.x;
    const int t  = threadIdx.x;

    if (bx >= GEMM_BLKS) {
        // ---- bhist part ----
        int* hist = (int*)smem;
        const int b = bx - GEMM_BLKS;
        for (int i = t; i < NBK2; i += FBLK) hist[i] = 0;
        __syncthreads();
        const int e0 = b * EPB;
        int e1 = e0 + EPB; if (e1 > EE) e1 = EE;
        for (int e = e0 + t; e < e1; e += FBLK)
            atomicAdd(&hist[dst[e] >> 8], 1);
        __syncthreads();
        for (int i = t; i < NBK2; i += FBLK)
            gHist[i * NCH + b] = hist[i];
        return;
    }

    const int rowBase = bx * 128;

    // ---- stage A: feat rows -> fp16 LDS tile, coalesced float4 loads ----
#pragma unroll
    for (int i = 0; i < 8; ++i) {
        int idx  = i * FBLK + t;          // 0..4095
        int r    = idx >> 5;              // 0..127
        int c4   = idx & 31;              // float4 column
        int rowg = rowBase + r;
        float4 f = (rowg < NN)
                       ? ((const float4*)(feat + (size_t)rowg * DIM))[c4]
                       : make_float4(0.f, 0.f, 0.f, 0.f);
        half4v h;
        h[0] = (_Float16)f.x; h[1] = (_Float16)f.y;
        h[2] = (_Float16)f.z; h[3] = (_Float16)f.w;
        *(half4v*)(smem + r * LDS_ROW + c4 * 8) = h;
    }
    // ---- stage B: Bt (fp16) -> LDS tile, coalesced int4 loads ----
#pragma unroll
    for (int i = 0; i < 4; ++i) {
        int idx = i * FBLK + t;           // 0..2047
        int r   = idx >> 4;               // 0..127
        int c8  = idx & 15;               // 16-B chunk
        int4 v = ((const int4*)(Bt + (size_t)r * DIM))[c8];
        *(int4*)(smem + LDS_B_OFF + r * LDS_ROW + c8 * 16) = v;
    }
    __syncthreads();

    const int lane = t & 63;
    const int wv   = t >> 6;              // 0..7
    const int l15  = lane & 15;
    const int quad = lane >> 4;
    const int row0 = rowBase + wv * 16;

    f32x4 acc[8];
#pragma unroll
    for (int nt = 0; nt < 8; ++nt) acc[nt] = (f32x4){0.f, 0.f, 0.f, 0.f};

    const char* Abase = smem + (wv * 16 + l15) * LDS_ROW + quad * 16;
    const char* Bbase = smem + LDS_B_OFF + l15 * LDS_ROW + quad * 16;

#pragma unroll
    for (int kc = 0; kc < 4; ++kc) {
        half8 a = *(const half8*)(Abase + kc * 64);
#pragma unroll
        for (int nt = 0; nt < 8; ++nt) {
            half8 b = *(const half8*)(Bbase + nt * 16 * LDS_ROW + kc * 64);
            acc[nt] = __builtin_amdgcn_mfma_f32_16x16x32_f16(a, b, acc[nt], 0, 0, 0);
        }
    }

    float avv[8];
#pragma unroll
    for (int nt = 0; nt < 8; ++nt) avv[nt] = attn[nt * 16 + l15];

    // epilogue: attention score + int8 quantization, staged via LDS
    char* qslice = smem + wv * (16 * LDS_ROW);   // wave's dead A-slice
#pragma unroll
    for (int r = 0; r < 4; ++r) {
        int row = row0 + quad * 4 + r;
        float p = 0.f, m = 0.f;
#pragma unroll
        for (int nt = 0; nt < 8; ++nt) {
            p += acc[nt][r] * avv[nt];
            m = fmaxf(m, fabsf(acc[nt][r]));
        }
        p += __shfl_xor(p, 1, 64);
        p += __shfl_xor(p, 2, 64);
        p += __shfl_xor(p, 4, 64);
        p += __shfl_xor(p, 8, 64);
        m = fmaxf(m, __shfl_xor(m, 1, 64));
        m = fmaxf(m, __shfl_xor(m, 2, 64));
        m = fmaxf(m, __shfl_xor(m, 4, 64));
        m = fmaxf(m, __shfl_xor(m, 8, 64));
        if (l15 == 0 && row < NN) {
            float lr = (p > 0.f) ? p : 0.01f * p;
            sv16[row] = (_Float16)__expf(lr);   // softmax numerator, fp16
            scf[row]  = m * (1.f / 127.f);      // per-row dequant scale
        }
        const float inv_s = (m > 0.f) ? (127.f / m) : 0.f;
#pragma unroll
        for (int nt = 0; nt < 8; ++nt) {
            float qv = rintf(acc[nt][r] * inv_s);
            qv = fminf(fmaxf(qv, -127.f), 127.f);
            qslice[(quad * 4 + r) * 128 + nt * 16 + l15] = (signed char)(int)qv;
        }
    }
    // coalesced writeback: lane covers 32 contiguous bytes of one row
    {
        const int rowg = row0 + (lane >> 2);
        if (rowg < NN) {
            int4 v0 = *(const int4*)(qslice + lane * 32);
            int4 v1 = *(const int4*)(qslice + lane * 32 + 16);
            int4* dp = (int4*)(hq + (size_t)rowg * DIM + (lane & 3) * 32);
            dp[0] = v0;
            dp[1] = v1;
        }
    }
}

// ---------------------------------------------------------------------------
// Kernel 2: exclusive scan of gHist (SCN = 98*1024 elements). Per-block sums
// land in bsum; consumers inline the 98-element bsum scan themselves.
// ---------------------------------------------------------------------------
__global__ __launch_bounds__(256) void k_scan_a(const int* __restrict__ deg,
                                                int* __restrict__ excl,
                                                int* __restrict__ bsum) {
    __shared__ int wsum[4];
    __shared__ int woff[4];
    const int t = threadIdx.x, b = blockIdx.x;
    const int base = b * 1024 + t * 4;
    int v0 = deg[base + 0];
    int v1 = deg[base + 1];
    int v2 = deg[base + 2];
    int v3 = deg[base + 3];
    int tsum = v0 + v1 + v2 + v3;

    const int lane = t & 63, w = t >> 6;
    int incl = tsum;
#pragma unroll
    for (int d = 1; d < 64; d <<= 1) {
        int n = __shfl_up(incl, d, 64);
        if (lane >= d) incl += n;
    }
    if (lane == 63) wsum[w] = incl;
    __syncthreads();
    if (t == 0) {
        int run = 0;
#pragma unroll
        for (int i = 0; i < 4; ++i) { woff[i] = run; run += wsum[i]; }
        bsum[b] = run;
    }
    __syncthreads();
    int texcl = incl - tsum + woff[w];
    excl[base + 0] = texcl;
    excl[base + 1] = texcl + v0;
    excl[base + 2] = texcl + v0 + v1;
    excl[base + 3] = texcl + v0 + v1 + v2;
}

// ---------------------------------------------------------------------------
// Inline 98-element exclusive scan of bsum into sboff (needs >=128 threads,
// two __syncthreads). Replaces a separate launch.
// ---------------------------------------------------------------------------
#define INLINE_BOFF_SCAN(bsum, sboff, swtop, t)                          \
    {                                                                    \
        const int lane_ = (t) & 63;                                      \
        int v_ = 0, incl_ = 0;                                           \
        if ((t) < 128) {                                                 \
            v_ = ((t) < NSB) ? (bsum)[(t)] : 0;                          \
            incl_ = v_;                                                  \
            _Pragma("unroll")                                            \
            for (int d_ = 1; d_ < 64; d_ <<= 1) {                        \
                int n_ = __shfl_up(incl_, d_, 64);                       \
                if (lane_ >= d_) incl_ += n_;                            \
            }                                                            \
            if ((t) == 63) (swtop) = incl_;                              \
        }                                                                \
        __syncthreads();                                                 \
        if ((t) < NSB) {                                                 \
            int add_ = ((t) >= 64) ? (swtop) : 0;                        \
            (sboff)[(t)] = incl_ - v_ + add_;                            \
        }                                                                \
        __syncthreads();                                                 \
    }

// ---------------------------------------------------------------------------
// Kernel 3: partition scatter. Private contiguous region per (bucket,block)
// -> full-line writebacks, LDS-only atomics. boff scan inlined.
// Payload: u32 = src | dloc<<17 (weight NOT carried — k_group reads sv16).
// ---------------------------------------------------------------------------
__global__ __launch_bounds__(1024) void k_bscatter(const int* __restrict__ src,
                                                   const int* __restrict__ dst,
                                                   const int* __restrict__ gOff,
                                                   const int* __restrict__ bsum,
                                                   unsigned* __restrict__ binned) {
    __shared__ int cur[NBK2];
    __shared__ int sboff[NSB];
    __shared__ int swtop;
    const int t = threadIdx.x, b = blockIdx.x;

    INLINE_BOFF_SCAN(bsum, sboff, swtop, t)

    for (int i = t; i < NBK2; i += 1024) {
        int idx = i * NCH + b;
        cur[i] = gOff[idx] + sboff[idx >> 10];
    }
    __syncthreads();
    const int e0 = b * EPB;
    int e1 = e0 + EPB; if (e1 > EE) e1 = EE;
    for (int e = e0 + t; e < e1; e += 1024) {
        int d  = dst[e];
        int si = src[e];
        int bk   = d >> 8;
        int dloc = d & (BK - 1);
        int pos = atomicAdd(&cur[bk], 1);
        binned[pos] = (unsigned)si | ((unsigned)dloc << 17);
    }
}

// ---------------------------------------------------------------------------
// Kernel 4: per-bucket exact CSR placement + node CSR pointers + per-node
// weight-sum (softmax denominator) via LDS f32 atomics. The pack weight is
// PRE-SCALED: w' = fp16(w * scf[src]) — int8 dequant folded into the edge
// weight, so k_agg's inner loop needs no scale lookups.
// ---------------------------------------------------------------------------
__global__ __launch_bounds__(1024) void k_group(const int* __restrict__ gOff,
                                                const int* __restrict__ bsum,
                                                const unsigned* __restrict__ binned,
                                                const _Float16* __restrict__ sv16,
                                                const float* __restrict__ scf,
                                                unsigned* __restrict__ pack,
                                                int* __restrict__ offs,
                                                float* __restrict__ lsum) {
    __shared__ int ldeg[BK];
    __shared__ float lsumSh[BK];
    __shared__ int wpart[4];
    __shared__ int sboff[NSB];
    __shared__ int swtop;
    const int bk = blockIdx.x;
    const int t  = threadIdx.x;

    INLINE_BOFF_SCAN(bsum, sboff, swtop, t)

    const int i0 = bk * NCH;
    const int base = gOff[i0] + sboff[i0 >> 10];
    int endp;
    if (bk == NBK2 - 1) endp = EE;
    else {
        int i1 = (bk + 1) * NCH;
        endp = gOff[i1] + sboff[i1 >> 10];
    }

    if (t < BK) { ldeg[t] = 0; lsumSh[t] = 0.f; }
    __syncthreads();
    for (int j = base + t; j < endp; j += 1024)
        atomicAdd(&ldeg[(binned[j] >> 17) & (BK - 1)], 1);
    __syncthreads();

    // scan of 256 bins: first 256 threads (4 waves) + cross-wave combine
    int v = 0, incl = 0;
    const int lane = t & 63;
    if (t < BK) {
        v = ldeg[t];
        incl = v;
#pragma unroll
        for (int d = 1; d < 64; d <<= 1) {
            int n = __shfl_up(incl, d, 64);
            if (lane >= d) incl += n;
        }
        if (lane == 63) wpart[t >> 6] = incl;
    }
    __syncthreads();
    if (t == 0) {
        int run = 0;
#pragma unroll
        for (int i = 0; i < 4; ++i) { int tmp = wpart[i]; wpart[i] = run; run += tmp; }
    }
    __syncthreads();
    if (t < BK) {
        int excl = incl - v + wpart[t >> 6];
        int c = base + excl;
        int n = bk * BK + t;
        if (n < NN) offs[n] = c;
        ldeg[t] = c;                       // becomes the placement cursor
    }
    if (bk == NBK2 - 1 && t == 0) offs[NN] = EE;
    __syncthreads();

    for (int j = base + t; j < endp; j += 1024) {
        unsigned e = binned[j];
        int dloc = (e >> 17) & (BK - 1);
        int si   = e & SRC_MASK;
        float w  = (float)sv16[si];
        float sc = scf[si];
        unsigned short wb =
            __builtin_bit_cast(unsigned short, (_Float16)(w * sc));
        atomicAdd(&lsumSh[dloc], w);
        int pos = atomicAdd(&ldeg[dloc], 1);
        pack[pos] = (unsigned)si | ((unsigned)wb << 17);
    }
    __syncthreads();
    if (t < BK) {
        int n = bk * BK + t;
        if (n < NN) lsum[n] = lsumSh[t];
    }
}

// ---------------------------------------------------------------------------
// Kernel 5 (v7): one wave per dst node, int8 rows, shfl-free inner loop,
// graduated tail (ceil(rem/4) predicated steps — measured 43.5 vs 44.0 for
// the fixed 16-slot tail in round 12).
// ---------------------------------------------------------------------------
#define TAIL_STEP(S)                                                        \
    {                                                                       \
        int idx_ = p + (S) * 4 + g;                                         \
        bool ok_ = idx_ < end;                                              \
        unsigned eb_ = pack[ok_ ? idx_ : last];                             \
        char8 q_ = *(const char8*)(hb + ((size_t)(eb_ & SRC_MASK) << 7));   \
        float wg_ = ok_ ? (float)__builtin_bit_cast(                        \
                              _Float16, (unsigned short)(eb_ >> 17))        \
                        : 0.f;                                              \
        _Pragma("unroll")                                                   \
        for (int k_ = 0; k_ < 8; ++k_)                                      \
            acc[k_] = fmaf((float)q_[k_], wg_, acc[k_]);                    \
    }

__global__ __launch_bounds__(256) void k_agg(const signed char* __restrict__ hq,
                                             const int* __restrict__ offs,
                                             const unsigned* __restrict__ pack,
                                             const float* __restrict__ lsum,
                                             float* __restrict__ out) {
    const int lane = threadIdx.x & 63;
    const int g    = lane >> 4;        // quarter-wave group 0..3
    const int li   = lane & 15;        // lane within group
    const int wid  = __builtin_amdgcn_readfirstlane(blockIdx.x * 4 + (threadIdx.x >> 6));
    if (wid >= NN) return;
    const int beg = __builtin_amdgcn_readfirstlane(offs[wid]);
    const int end = __builtin_amdgcn_readfirstlane(offs[wid + 1]);

    const signed char* hb = hq + li * 8;   // per-lane base (hoisted)
    float acc[8];
#pragma unroll
    for (int k = 0; k < 8; ++k) acc[k] = 0.f;

    int p = beg;
    // main: 16 edges per iteration, 4 gathers in flight, no predication
    for (; p + 16 <= end; p += 16) {
        unsigned eb[4];
#pragma unroll
        for (int s = 0; s < 4; ++s) eb[s] = pack[p + s * 4 + g];
        char8 q[4];
#pragma unroll
        for (int s = 0; s < 4; ++s)
            q[s] = *(const char8*)(hb + ((size_t)(eb[s] & SRC_MASK) << 7));
        float wg[4];
#pragma unroll
        for (int s = 0; s < 4; ++s)
            wg[s] = (float)__builtin_bit_cast(_Float16,
                                              (unsigned short)(eb[s] >> 17));
#pragma unroll
        for (int s = 0; s < 4; ++s)
#pragma unroll
            for (int k = 0; k < 8; ++k)
                acc[k] = fmaf((float)q[s][k], wg[s], acc[k]);
    }
    // graduated tail: ceil(rem/4) independent steps, wave-uniform branches
    const int rem = end - p;            // 0..15
    if (rem > 0) {
        const int last = end - 1;
        if (rem > 12)      { TAIL_STEP(0) TAIL_STEP(1) TAIL_STEP(2) TAIL_STEP(3) }
        else if (rem > 8)  { TAIL_STEP(0) TAIL_STEP(1) TAIL_STEP(2) }
        else if (rem > 4)  { TAIL_STEP(0) TAIL_STEP(1) }
        else               { TAIL_STEP(0) }
    }

    // cross-group combine: 4 groups hold partials for the same channels
#pragma unroll
    for (int k = 0; k < 8; ++k) {
        acc[k] += __shfl_xor(acc[k], 16, 64);
        acc[k] += __shfl_xor(acc[k], 32, 64);
    }

    const float l   = lsum[wid];
    const float inv = (l > 0.f) ? (1.0f / l) : 0.f;

    // store: group 0's 16 lanes write 32 B each -> contiguous 512 B per node
    if (g == 0) {
        float4 o0, o1;
        o0.x = fmaxf(acc[0] * inv, 0.f);
        o0.y = fmaxf(acc[1] * inv, 0.f);
        o0.z = fmaxf(acc[2] * inv, 0.f);
        o0.w = fmaxf(acc[3] * inv, 0.f);
        o1.x = fmaxf(acc[4] * inv, 0.f);
        o1.y = fmaxf(acc[5] * inv, 0.f);
        o1.z = fmaxf(acc[6] * inv, 0.f);
        o1.w = fmaxf(acc[7] * inv, 0.f);
        float4* op = (float4*)(out + (size_t)wid * DIM + li * 8);
        op[0] = o0;
        op[1] = o1;
    }
}

// ---------------------------------------------------------------------------
extern "C" void kernel_launch(void* const* d_in, const int* in_sizes, int n_in,
                              void* d_out, int out_size, void* d_ws, size_t ws_size,
                              hipStream_t stream) {
    const float* feat = (const float*)d_in[0];
    const float* mask = (const float*)d_in[1];
    const float* W    = (const float*)d_in[2];
    const float* attn = (const float*)d_in[3];
    const int*   src  = (const int*)d_in[4];
    const int*   dst  = (const int*)d_in[5];
    float* out = (float*)d_out;

    // Workspace carve-up (~28 MB total)
    char* ws = (char*)d_ws;
    size_t off = 0;
    auto alloc = [&](size_t bytes) -> void* {
        void* p = ws + off;
        off = (off + bytes + 511) & ~(size_t)511;
        return p;
    };
    signed char* hq  = (signed char*)alloc((size_t)NN * DIM);   // 12.8 MB
    float*   scf  = (float*)alloc((size_t)NN * 4);              // 0.4 MB
    float*   lsum = (float*)alloc((size_t)NN * 4);              // 0.4 MB
    _Float16* sv16 = (_Float16*)alloc((size_t)NN * 2);          // 0.2 MB
    _Float16* Bt   = (_Float16*)alloc((size_t)DIM * DIM * 2);
    int*     gOff  = (int*)alloc((size_t)SCN * 4);              // 401 KB
    int*     offs  = (int*)alloc((size_t)(NN + 1) * 4);
    int*     bsum  = (int*)alloc((size_t)NSB * 4);
    unsigned* binned = (unsigned*)alloc((size_t)EE * 4);        // 6.4 MB
    unsigned* pack   = (unsigned*)alloc((size_t)EE * 4);        // 6.4 MB

    k_wt<<<(DIM * DIM + 255) / 256, 256, 0, stream>>>(W, mask, Bt);
    k_front<<<GEMM_BLKS + NCH, FBLK, 0, stream>>>(feat, Bt, attn, hq, scf,
                                                  sv16, dst, gOff);
    k_scan_a<<<NSB, 256, 0, stream>>>(gOff, gOff, bsum);
    k_bscatter<<<NCH, 1024, 0, stream>>>(src, dst, gOff, bsum, binned);
    k_group<<<NBK2, 1024, 0, stream>>>(gOff, bsum, binned, sv16, scf,
                                       pack, offs, lsum);
    k_agg<<<(NN + 3) / 4, 256, 0, stream>>>(hq, offs, pack, lsum, out);
}